// Round 8
// baseline (1067.681 us; speedup 1.0000x reference)
//
#include <hip/hip_runtime.h>
#include <math.h>

#define B_  32
#define LT_ 512
#define LI_ 576
#define LIP 640           // image tokens padded to a multiple of 128
#define D_  768
#define H_  8
#define K_  512
#define NTOK  (LI_ + LT_) // 1088
#define CSPLIT 8
#define TPB   (NTOK / CSPLIT)  // 136 tokens per ctx block
#define NHEAD ((long)H_ * B_ * D_)

typedef __attribute__((ext_vector_type(4))) short short4v;
typedef __attribute__((ext_vector_type(8))) unsigned short ushort8;
typedef __attribute__((ext_vector_type(8))) _Float16 f16x8;
typedef __attribute__((ext_vector_type(4))) float f32x4;

__device__ __forceinline__ unsigned short f2h(float x) {
  _Float16 h = (_Float16)x;                       // RNE
  return __builtin_bit_cast(unsigned short, h);
}
__device__ __forceinline__ float h2f(unsigned short u) {
  return (float)__builtin_bit_cast(_Float16, u);
}
__device__ __forceinline__ float ftanh(float x) {
  float e = __expf(2.f * x);                      // saturates correctly at +-inf
  return 1.f - 2.f * __builtin_amdgcn_rcpf(e + 1.f);
}

__device__ __forceinline__ void gl_lds16(const void* g, void* l) {
  __builtin_amdgcn_global_load_lds(
      (const __attribute__((address_space(1))) void*)g,
      (__attribute__((address_space(3))) void*)l, 16, 0, 0);
}

// ---------------------------------------------------------------------------
// Segmented NT fp16 MFMA GEMM: C[m,n] = sum_k A[m*lda+k]*B[n*ldb+k], k<Kd
// Block tile 256x128, BK=32, 4 waves each owning 128x64 (2x2 wave grid).
// TRIPLE-BUFFERED LDS (3 x 24KB) + counted-vmcnt pipeline (T3+T4 recipe):
//   prologue: stage(buf0,t0) stage(buf1,t1) stage(buf2,t2)   // 18 loads
//   iter t:   s_waitcnt vmcnt(12|6|0)  (own stage(t) done, 2 tiles in flight)
//             s_barrier               (all waves' slices landed)
//             ds_read buf[t%3]; MFMA (setprio 1)
//             s_barrier               (all reads of buf[t%3] drained)
//             stage(buf[t%3], t+3)    (restage just-consumed buffer)
// vmcnt never drains to 0 in steady state (T4). asm "memory" clobbers pin
// the LDS reads between the barriers against compiler motion (rule #18).
// LDS k-slot swizzle (m97 BK=32 form): slot = chunk ^ ((row>>1)&3), applied
// to the global source column on write and to the read slot (rule #21).
// XCD-swizzled 1D grid (m204). Up to 3 independent segments per dispatch.
// epi: 0=PLAIN fp16 C; 1=T fp16 C + C^T; 2=TANH-dot accumulate; 3=OUT atomic f32
// ---------------------------------------------------------------------------
#define EPI_PLAIN 0
#define EPI_T     1
#define EPI_TANH  2
#define EPI_OUT   3

struct Seg {
  const unsigned short *A, *B;
  unsigned short *C, *CT;
  const unsigned short* base;
  const float* wvec;
  float* outv;
  long sA, sB, sC, sCT, sBase;
  int Kd, lda, ldb;          // lda/ldb: physical row strides (== Kd unless split-K)
  int gx, gy, nblk, epi, Mlim, valid, ldc, ldt;
};
struct Params { Seg s0, s1, s2; };

__global__ __launch_bounds__(256, 2) void mfma_seg(Params p)
{
  // bijective XCD-aware swizzle (m204)
  const int orig = blockIdx.x, nwg = gridDim.x;
  const int q8 = nwg >> 3, r8 = nwg & 7;
  const int xcd = orig & 7, idx = orig >> 3;
  const int wg = (xcd < r8 ? xcd * (q8 + 1) : r8 * (q8 + 1) + (xcd - r8) * q8) + idx;

  Seg sg; int local;
  if (wg < p.s0.nblk)                      { sg = p.s0; local = wg; }
  else if (wg < p.s0.nblk + p.s1.nblk)     { sg = p.s1; local = wg - p.s0.nblk; }
  else                                     { sg = p.s2; local = wg - p.s0.nblk - p.s1.nblk; }

  const int bx = local % sg.gx;
  const int tmp2 = local / sg.gx;
  const int by = tmp2 % sg.gy, bz = tmp2 / sg.gy;

  // 72 KB: three buffers of {A 256x32 (16KB) | B 128x32 (8KB)}
  __shared__ unsigned short LDSU[36864];

  const int t = threadIdx.x, lane = t & 63, w = t >> 6;
  const int wr = w >> 1, wc = w & 1;
  const int m0 = bx * 256, n0 = by * 128;
  const int Kd = sg.Kd, lda = sg.lda, ldb = sg.ldb, ldc = sg.ldc;
  const unsigned short* A  = sg.A + (long)bz * sg.sA;
  const unsigned short* Bm = sg.B + (long)bz * sg.sB;

  // staging: one gl_lds16 covers 16 rows (row stride 64B). lane l ->
  // row-in-issue = l>>2, chunk = l&3. issue q: A rows q*64+rowb (q<4),
  // B rows q*64+rowb (q<2). source col pre-swizzled: chunk ^ ((row>>1)&3)
  // (q*64 keeps (row>>1)&3 invariant). per-lane LDS ptr == base + lane*16B.
  const int rowb = w * 16 + (lane >> 2);
  const int cswz = ((lane & 3) ^ ((rowb >> 1) & 3)) * 8;
  const bool clampA = (m0 + 256 > sg.Mlim);
  const unsigned short* aSrc = A  + (long)(m0 + rowb) * lda + cswz;
  const unsigned short* bSrc = Bm + (long)(n0 + rowb) * ldb + cswz;
  const int ldsLane = rowb * 32;                  // ushort offset within tile

  f32x4 acc[8][4];
  #pragma unroll
  for (int i = 0; i < 8; ++i)
    #pragma unroll
    for (int j = 0; j < 4; ++j)
      acc[i][j] = (f32x4){0.f, 0.f, 0.f, 0.f};

  const int rl = lane & 15, g = lane >> 4;
  const int aslot = (g ^ ((rl >> 1) & 3)) << 3;

  auto stage = [&](int bufi, int k0) {
    unsigned short* Ab = LDSU + bufi * 12288;
    unsigned short* Bb = Ab + 8192;
    if (!clampA) {
      #pragma unroll
      for (int q = 0; q < 4; ++q)
        gl_lds16(aSrc + (long)q * 64 * lda + k0, Ab + ldsLane + q * 2048);
    } else {
      #pragma unroll
      for (int q = 0; q < 4; ++q) {
        int rgl = m0 + q * 64 + rowb;
        if (rgl >= sg.Mlim) rgl = sg.Mlim - 1;
        gl_lds16(A + (long)rgl * lda + cswz + k0, Ab + ldsLane + q * 2048);
      }
    }
    #pragma unroll
    for (int q = 0; q < 2; ++q)
      gl_lds16(bSrc + (long)q * 64 * ldb + k0, Bb + ldsLane + q * 2048);
  };

  const int nt = Kd >> 5;
  stage(0, 0);
  if (nt > 1) stage(1, 32);
  if (nt > 2) stage(2, 64);
  int cur = 0;
  for (int tt = 0; tt < nt; ++tt) {
    // gate: own stage(tt) complete; keep up to 2 future tiles in flight (T4)
    const int ahead = nt - 1 - tt;
    if (ahead >= 2)      asm volatile("s_waitcnt vmcnt(12)" ::: "memory");
    else if (ahead == 1) asm volatile("s_waitcnt vmcnt(6)"  ::: "memory");
    else                 asm volatile("s_waitcnt vmcnt(0)"  ::: "memory");
    __builtin_amdgcn_s_barrier();           // all waves' stage(tt) landed
    asm volatile("" ::: "memory");          // reads stay below this point

    const unsigned short* Ab = LDSU + cur * 12288;
    const unsigned short* Bb = Ab + 8192;
    f16x8 af[8], bf[4];
    #pragma unroll
    for (int i = 0; i < 8; ++i)
      af[i] = *(const f16x8*)&Ab[(wr * 128 + i * 16 + rl) * 32 + aslot];
    #pragma unroll
    for (int j = 0; j < 4; ++j)
      bf[j] = *(const f16x8*)&Bb[(wc * 64 + j * 16 + rl) * 32 + aslot];
    __builtin_amdgcn_s_setprio(1);
    #pragma unroll
    for (int i = 0; i < 8; ++i)
      #pragma unroll
      for (int j = 0; j < 4; ++j)
        acc[i][j] = __builtin_amdgcn_mfma_f32_16x16x32_f16(af[i], bf[j], acc[i][j], 0, 0, 0);
    __builtin_amdgcn_s_setprio(0);

    asm volatile("" ::: "memory");          // reads stay above this point
    __builtin_amdgcn_s_barrier();           // all waves done reading buf[cur]
    if (tt + 3 < nt) stage(cur, (tt + 3) << 5);   // restage consumed buffer
    cur = (cur == 2) ? 0 : cur + 1;
  }

  const int rg = lane >> 4;
  if (sg.epi <= EPI_T) {
    unsigned short* C = sg.C + (long)bz * sg.sC;
    #pragma unroll
    for (int i = 0; i < 8; ++i)
      #pragma unroll
      for (int j = 0; j < 4; ++j)
        #pragma unroll
        for (int rr = 0; rr < 4; ++rr) {
          int ml = wr * 128 + i * 16 + rg * 4 + rr;   // C/D: row=(l>>4)*4+reg
          int nl = wc * 64 + j * 16 + rl;             //      col=l&15
          if (m0 + ml < sg.Mlim)
            C[(long)(m0 + ml) * ldc + n0 + nl] = f2h(acc[i][j][rr]);
        }
    if (sg.epi == EPI_T) {
      unsigned short* CT = sg.CT + (long)bz * sg.sCT;
      __syncthreads();                       // all LDS K-loop reads done
      #pragma unroll
      for (int pp = 0; pp < 2; ++pp) {       // m-half pp
        if (wr == pp) {
          #pragma unroll
          for (int i = 0; i < 8; ++i)
            #pragma unroll
            for (int j = 0; j < 4; ++j) {
              int nl = wc * 64 + j * 16 + rl;
              int mh = i * 16 + rg * 4;
              *(short4v*)&LDSU[nl * 136 + mh] = (short4v){
                  (short)f2h(acc[i][j][0]), (short)f2h(acc[i][j][1]),
                  (short)f2h(acc[i][j][2]), (short)f2h(acc[i][j][3])};
            }
        }
        __syncthreads();
        #pragma unroll
        for (int rr = 0; rr < 8; ++rr) {
          int rn = rr * 16 + (t >> 4);
          int m8 = (t & 15) * 8;
          int mg = m0 + pp * 128 + m8;
          if (mg < sg.Mlim)
            *(ushort8*)(CT + (long)(n0 + rn) * sg.ldt + mg) =
                *(const ushort8*)&LDSU[rn * 136 + m8];
        }
        __syncthreads();
      }
    }
  } else if (sg.epi == EPI_TANH) {
    const unsigned short* base = sg.base + (long)bz * sg.sBase;
    float* outp = sg.outv + (long)bz * sg.valid;
    #pragma unroll
    for (int i = 0; i < 8; ++i)
      #pragma unroll
      for (int rr = 0; rr < 4; ++rr) {
        int row = m0 + wr * 128 + i * 16 + rg * 4 + rr;  // uniform over rl group
        if (row < sg.Mlim) {
          float s = 0.f;
          #pragma unroll
          for (int j = 0; j < 4; ++j) {
            int col = n0 + wc * 64 + j * 16 + rl;
            float v = acc[i][j][rr] + h2f(base[(long)row * ldc + col]);
            s += ftanh(v) * sg.wvec[col];
          }
          s += __shfl_xor(s, 1, 64);
          s += __shfl_xor(s, 2, 64);
          s += __shfl_xor(s, 4, 64);
          s += __shfl_xor(s, 8, 64);
          if (rl == 0 && row < sg.valid)
            atomicAdd(&outp[row], s);
        }
      }
  } else {  // EPI_OUT: rows < 32 live in wr==0, i<2
    float* outp = sg.outv;
    if (wr == 0) {
      #pragma unroll
      for (int i = 0; i < 2; ++i)
        #pragma unroll
        for (int rr = 0; rr < 4; ++rr) {
          int row = i * 16 + rg * 4 + rr;
          #pragma unroll
          for (int j = 0; j < 4; ++j) {
            int col = n0 + wc * 64 + j * 16 + rl;
            atomicAdd(&outp[(long)row * ldc + col], acc[i][j][rr]);
          }
        }
    }
  }
}

// --------------------------- helper kernels --------------------------------
struct CSeg { const float* src; unsigned short* dst; long n8; };

__global__ __launch_bounds__(256) void cast_multi(
    CSeg c0, CSeg c1, CSeg c2, CSeg c3, CSeg c4)
{
  long i = (long)blockIdx.x * 256 + threadIdx.x;
  const float* src; unsigned short* dst;
  if      (i < c0.n8)                 { src = c0.src; dst = c0.dst; }
  else if ((i -= c0.n8) < c1.n8)      { src = c1.src; dst = c1.dst; }
  else if ((i -= c1.n8) < c2.n8)      { src = c2.src; dst = c2.dst; }
  else if ((i -= c2.n8) < c3.n8)      { src = c3.src; dst = c3.dst; }
  else if ((i -= c3.n8) < c4.n8)      { src = c4.src; dst = c4.dst; }
  else return;
  float4 v0 = ((const float4*)src)[i * 2];
  float4 v1 = ((const float4*)src)[i * 2 + 1];
  ushort8 o;
  o[0] = f2h(v0.x); o[1] = f2h(v0.y); o[2] = f2h(v0.z); o[3] = f2h(v0.w);
  o[4] = f2h(v1.x); o[5] = f2h(v1.y); o[6] = f2h(v1.z); o[7] = f2h(v1.w);
  *(ushort8*)(dst + i * 8) = o;
}

__global__ __launch_bounds__(256) void cast_pad_image(
    const float* __restrict__ in, unsigned short* __restrict__ out)
{
  long tid = (long)blockIdx.x * 256 + threadIdx.x;
  const long tot = (long)B_ * LIP * (D_ / 8);
  if (tid >= tot) return;
  int e8 = (int)(tid % (D_ / 8));
  long rw = tid / (D_ / 8);
  int y  = (int)(rw % LIP);
  long b = rw / LIP;
  ushort8 o;
  if (y < LI_) {
    const float* p = in + ((b * LI_ + y) * D_ + e8 * 8);
    float4 v0 = *(const float4*)p, v1 = *(const float4*)(p + 4);
    o[0] = f2h(v0.x); o[1] = f2h(v0.y); o[2] = f2h(v0.z); o[3] = f2h(v0.w);
    o[4] = f2h(v1.x); o[5] = f2h(v1.y); o[6] = f2h(v1.z); o[7] = f2h(v1.w);
  } else {
    #pragma unroll
    for (int j = 0; j < 8; ++j) o[j] = 0;
  }
  *(ushort8*)(out + rw * D_ + e8 * 8) = o;
}

__global__ __launch_bounds__(256) void zero_f32(float* __restrict__ p, long n) {
  long i = (long)blockIdx.x * 256 + threadIdx.x;
  if (i < n) p[i] = 0.f;
}

// out[b,d] = bo[d]  (bias pre-init; EPI_OUT accumulates on top)
__global__ __launch_bounds__(256) void init_out(
    const float* __restrict__ bo, float* __restrict__ out)
{
  int i = blockIdx.x * 256 + threadIdx.x;   // 96 blocks x 256 = 24576
  out[i] = bo[i % D_];
}

// per (b,h): softmax over LI (lv) and LT (lq) -> normalized att weights
__global__ __launch_bounds__(256) void softmax_att(
    const float* __restrict__ lv, const float* __restrict__ lq,
    float* __restrict__ attvG, float* __restrict__ attqG)
{
  const int b = blockIdx.x, h = blockIdx.y;
  const int t = threadIdx.x;
  __shared__ float buf[LI_];
  __shared__ float red[4];

  const float* lvp = lv + ((long)h * B_ + b) * LI_;
  float m = -1e30f;
  for (int i = t; i < LI_; i += 256) m = fmaxf(m, lvp[i]);
  #pragma unroll
  for (int o = 32; o > 0; o >>= 1) m = fmaxf(m, __shfl_down(m, o, 64));
  if ((t & 63) == 0) red[t >> 6] = m;
  __syncthreads();
  m = fmaxf(fmaxf(red[0], red[1]), fmaxf(red[2], red[3]));
  __syncthreads();
  float s = 0.f;
  for (int i = t; i < LI_; i += 256) { float e = __expf(lvp[i] - m); buf[i] = e; s += e; }
  #pragma unroll
  for (int o = 32; o > 0; o >>= 1) s += __shfl_down(s, o, 64);
  if ((t & 63) == 0) red[t >> 6] = s;
  __syncthreads();
  s = red[0] + red[1] + red[2] + red[3];
  {
    float inv = 1.f / s;
    float* op = attvG + ((long)h * B_ + b) * LI_;
    for (int i = t; i < LI_; i += 256) op[i] = buf[i] * inv;
  }
  __syncthreads();

  const float* lqp = lq + ((long)h * B_ + b) * LT_;
  m = -1e30f;
  for (int i = t; i < LT_; i += 256) m = fmaxf(m, lqp[i]);
  #pragma unroll
  for (int o = 32; o > 0; o >>= 1) m = fmaxf(m, __shfl_down(m, o, 64));
  if ((t & 63) == 0) red[t >> 6] = m;
  __syncthreads();
  m = fmaxf(fmaxf(red[0], red[1]), fmaxf(red[2], red[3]));
  __syncthreads();
  s = 0.f;
  for (int i = t; i < LT_; i += 256) { float e = __expf(lqp[i] - m); buf[i] = e; s += e; }
  #pragma unroll
  for (int o = 32; o > 0; o >>= 1) s += __shfl_down(s, o, 64);
  if ((t & 63) == 0) red[t >> 6] = s;
  __syncthreads();
  s = red[0] + red[1] + red[2] + red[3];
  {
    float inv = 1.f / s;
    float* op = attqG + ((long)h * B_ + b) * LT_;
    for (int i = t; i < LT_; i += 256) op[i] = buf[i] * inv;
  }
}

// partial context: grid (B, D/128, CSPLIT); 256 thr = 128 d-lanes x 2 groups.
__global__ __launch_bounds__(256) void ctx_part(
    const float* __restrict__ attvG, const float* __restrict__ attqG,
    const unsigned short* __restrict__ text_h,   // base; image_p follows
    float* __restrict__ head_part)
{
  const int b = blockIdx.x, d0 = blockIdx.y * 128, s = blockIdx.z;
  const int t = threadIdx.x, dl = t & 127, g = t >> 7;
  const long IMG_OFF = (long)B_ * LT_ * D_;
  __shared__ float wts[H_][TPB];
  __shared__ long  roff[TPB];
  __shared__ float red[H_][128];
  const int tok0 = s * TPB;
  for (int i = t; i < H_ * TPB; i += 256) {
    int h = i / TPB, j = i % TPB, tok = tok0 + j;
    wts[h][j] = tok < LI_ ? attvG[((long)h * B_ + b) * LI_ + tok]
                          : attqG[((long)h * B_ + b) * LT_ + (tok - LI_)];
  }
  if (t < TPB) {
    int tok = tok0 + t;
    roff[t] = tok < LI_ ? IMG_OFF + ((long)b * LIP + tok) * D_
                        : ((long)b * LT_ + (tok - LI_)) * D_;
  }
  __syncthreads();
  float acc[H_];
  #pragma unroll
  for (int h = 0; h < H_; ++h) acc[h] = 0.f;
  #pragma unroll 4
  for (int j = g; j < TPB; j += 2) {
    float val = h2f(text_h[roff[j] + d0 + dl]);
    #pragma unroll
    for (int h = 0; h < H_; ++h) acc[h] = fmaf(wts[h][j], val, acc[h]);
  }
  if (g == 1) {
    #pragma unroll
    for (int h = 0; h < H_; ++h) red[h][dl] = acc[h];
  }
  __syncthreads();
  if (g == 0) {
    float* hp = head_part + (long)s * NHEAD;
    #pragma unroll
    for (int h = 0; h < H_; ++h)
      hp[((long)h * B_ + b) * D_ + d0 + dl] = acc[h] + red[h][dl];
  }
}

// reduce partials -> head16[b][h*D+d] (fp16, layout ready for out-proj GEMM)
__global__ __launch_bounds__(256) void reduce_head(
    const float* __restrict__ head_part, unsigned short* __restrict__ head16)
{
  long i = (long)blockIdx.x * 256 + threadIdx.x;   // over [h][b][d]
  float s = 0.f;
  #pragma unroll
  for (int p = 0; p < CSPLIT; ++p) s += head_part[(long)p * NHEAD + i];
  int d = (int)(i % D_);
  long hb = i / D_;
  int b = (int)(hb % B_), h = (int)(hb / B_);
  head16[(long)b * (H_ * D_) + (long)h * D_ + d] = f2h(s);
}

// ---------------------------------------------------------------------------
extern "C" void kernel_launch(void* const* d_in, const int* in_sizes, int n_in,
                              void* d_out, int out_size, void* d_ws, size_t ws_size,
                              hipStream_t stream)
{
  const float* text  = (const float*)d_in[0];
  const float* image = (const float*)d_in[1];
  const float* Wb  = (const float*)d_in[3];
  const float* Wv  = (const float*)d_in[4];
  const float* Wq  = (const float*)d_in[5];
  const float* Whv = (const float*)d_in[6];
  const float* Whq = (const float*)d_in[7];
  const float* Wo  = (const float*)d_in[8];
  const float* bo  = (const float*)d_in[9];
  float* out = (float*)d_out;

  const long N_TEXT = (long)B_ * LT_ * D_;
  const long N_IMGP = (long)B_ * LIP * D_;
  const long N_WV   = (long)K_ * D_;
  const long N_WB   = (long)H_ * D_ * D_;
  const long N_WO   = (long)D_ * H_ * D_;
  const long N_WVV  = (long)B_ * LIP * K_;
  const long N_WQQ  = (long)B_ * LT_ * K_;
  const long N_PT   = (long)B_ * LT_ * D_;
  const long N_AFF  = (long)B_ * LT_ * LIP;
  const long N_LV   = (long)H_ * B_ * LI_;
  const long N_LQ   = (long)H_ * B_ * LT_;
  const long N_H16  = (long)B_ * H_ * D_;

  unsigned short* wsu = (unsigned short*)d_ws;
  long off = 0;
  unsigned short* text_h  = wsu + off; off += N_TEXT;
  unsigned short* image_p = wsu + off; off += N_IMGP;
  unsigned short* Wv_h    = wsu + off; off += N_WV;
  unsigned short* Wq_h    = wsu + off; off += N_WV;
  unsigned short* Wb_h    = wsu + off; off += N_WB;
  unsigned short* Wo_h    = wsu + off; off += N_WO;
  unsigned short* wv_v    = wsu + off; off += N_WVV;
  unsigned short* wq_q    = wsu + off; off += N_WQQ;
  unsigned short* wv_vT   = wsu + off; off += N_WVV;
  unsigned short* wq_qT   = wsu + off; off += N_WQQ;
  unsigned short* pt_h    = wsu + off; off += N_PT;
  unsigned short* aff     = wsu + off; off += N_AFF;
  unsigned short* affT    = wsu + off; off += N_AFF;
  unsigned short* head16  = wsu + off; off += N_H16;
  float* lv        = (float*)(wsu + off);
  float* lq        = lv + N_LV;
  float* attvG     = lq + N_LQ;
  float* attqG     = attvG + N_LV;
  float* head_part = attqG + N_LQ;
  const size_t need = (size_t)off * 2 +
      (size_t)(2 * (N_LV + N_LQ) + CSPLIT * NHEAD) * 4;
  if (ws_size < need) return;

  dim3 blk(256);

  // ---- casts (one merged dispatch + padded image) ----
  {
    CSeg c0{text, text_h, N_TEXT / 8};
    CSeg c1{Wv,   Wv_h,   N_WV / 8};
    CSeg c2{Wq,   Wq_h,   N_WV / 8};
    CSeg c3{Wb,   Wb_h,   N_WB / 8};
    CSeg c4{Wo,   Wo_h,   N_WO / 8};
    long tot8 = c0.n8 + c1.n8 + c2.n8 + c3.n8 + c4.n8;
    cast_multi<<<(unsigned)((tot8 + 255) / 256), blk, 0, stream>>>(c0, c1, c2, c3, c4);
  }
  cast_pad_image<<<(unsigned)((B_ * LIP * (D_ / 8) + 255) / 256), blk, 0, stream>>>(image, image_p);
  zero_f32<<<(unsigned)((N_LV + N_LQ + 255) / 256), blk, 0, stream>>>(lv, N_LV + N_LQ);
  init_out<<<(unsigned)(B_ * D_ / 256), blk, 0, stream>>>(bo, out);

  Seg zs{};  zs.nblk = 0;

  // ---- G1: wv_v(+T), wq_q(+T), pt[0] ----
  {
    Seg s0{}; s0.A = image_p; s0.B = Wv_h; s0.C = wv_v; s0.CT = wv_vT;
    s0.sA = (long)LIP * D_; s0.sC = (long)LIP * K_; s0.sCT = (long)K_ * LIP;
    s0.Kd = D_; s0.lda = D_; s0.ldb = D_;
    s0.gx = 3; s0.gy = 4; s0.nblk = 3 * 4 * B_; s0.epi = EPI_T;
    s0.Mlim = LIP; s0.ldc = K_; s0.ldt = LIP;

    Seg s1{}; s1.A = text_h; s1.B = Wq_h; s1.C = wq_q; s1.CT = wq_qT;
    s1.sA = (long)LT_ * D_; s1.sC = (long)LT_ * K_; s1.sCT = (long)K_ * LT_;
    s1.Kd = D_; s1.lda = D_; s1.ldb = D_;
    s1.gx = 2; s1.gy = 4; s1.nblk = 2 * 4 * B_; s1.epi = EPI_T;
    s1.Mlim = LT_; s1.ldc = K_; s1.ldt = LT_;

    Seg s2{}; s2.A = text_h; s2.B = Wb_h; s2.C = pt_h;
    s2.Kd = D_; s2.lda = D_; s2.ldb = D_;
    s2.gx = 64; s2.gy = 6; s2.nblk = 64 * 6; s2.epi = EPI_PLAIN;
    s2.Mlim = B_ * LT_; s2.ldc = D_;

    Params P{s0, s1, s2};
    mfma_seg<<<s0.nblk + s1.nblk + s2.nblk, blk, 0, stream>>>(P);
  }

  for (int h = 0; h < H_; ++h) {
    // aff[h] (+ affT)
    {
      Seg s0{}; s0.A = pt_h; s0.B = image_p; s0.C = aff; s0.CT = affT;
      s0.sA = (long)LT_ * D_; s0.sB = (long)LIP * D_;
      s0.sC = (long)LT_ * LIP; s0.sCT = (long)LIP * LT_;
      s0.Kd = D_; s0.lda = D_; s0.ldb = D_;
      s0.gx = 2; s0.gy = 5; s0.nblk = 2 * 5 * B_; s0.epi = EPI_T;
      s0.Mlim = LT_; s0.ldc = LIP; s0.ldt = LT_;
      Params P{s0, zs, zs};
      mfma_seg<<<s0.nblk, blk, 0, stream>>>(P);
    }
    // wqqc-tanh + wvvc-tanh + pt[h+1]
    {
      Seg s0{}; s0.A = affT; s0.B = wq_qT;
      s0.base = wv_v; s0.wvec = Whv; s0.outv = lv + (long)h * B_ * LI_;
      s0.sA = (long)LIP * LT_; s0.sB = (long)K_ * LT_; s0.sBase = (long)LIP * K_;
      s0.Kd = LT_; s0.lda = LT_; s0.ldb = LT_;
      s0.gx = 3; s0.gy = 4; s0.nblk = 3 * 4 * B_; s0.epi = EPI_TANH;
      s0.Mlim = LIP; s0.valid = LI_; s0.ldc = K_;

      Seg s1{}; s1.A = aff; s1.B = wv_vT;
      s1.base = wq_q; s1.wvec = Whq; s1.outv = lq + (long)h * B_ * LT_;
      s1.sA = (long)LT_ * LIP; s1.sB = (long)K_ * LIP; s1.sBase = (long)LT_ * K_;
      s1.Kd = LIP; s1.lda = LIP; s1.ldb = LIP;
      s1.gx = 2; s1.gy = 4; s1.nblk = 2 * 4 * B_; s1.epi = EPI_TANH;
      s1.Mlim = LT_; s1.valid = LT_; s1.ldc = K_;

      Seg s2 = zs;
      if (h < H_ - 1) {
        s2.A = text_h; s2.B = Wb_h + (long)(h + 1) * D_ * D_; s2.C = pt_h;
        s2.Kd = D_; s2.lda = D_; s2.ldb = D_;
        s2.gx = 64; s2.gy = 6; s2.nblk = 64 * 6; s2.epi = EPI_PLAIN;
        s2.Mlim = B_ * LT_; s2.ldc = D_;
      }
      Params P{s0, s1, s2};
      mfma_seg<<<s0.nblk + s1.nblk + s2.nblk, blk, 0, stream>>>(P);
    }
  }

  softmax_att<<<dim3(B_, H_), blk, 0, stream>>>(lv, lq, attvG, attqG);
  ctx_part<<<dim3(B_, D_ / 128, CSPLIT), blk, 0, stream>>>(attvG, attqG, text_h, head_part);
  reduce_head<<<(unsigned)(NHEAD / 256), blk, 0, stream>>>(head_part, head16);

  // out[b,d] += sum_k head16[b,k] * Wo_h[d,k]  (K split 8 ways via bz;
  // physical row stride H_*D_ decoupled from per-slice Kd)
  {
    Seg s0{}; s0.A = head16; s0.B = Wo_h; s0.outv = out;
    s0.sA = (long)(H_ * D_ / 8); s0.sB = (long)(H_ * D_ / 8);
    s0.Kd = H_ * D_ / 8; s0.lda = H_ * D_; s0.ldb = H_ * D_;
    s0.gx = 1; s0.gy = 6; s0.nblk = 1 * 6 * 8; s0.epi = EPI_OUT;
    s0.Mlim = B_; s0.valid = B_; s0.ldc = D_;
    Params P{s0, zs, zs};
    mfma_seg<<<s0.nblk, blk, 0, stream>>>(P);
  }
}

// Round 9
// 972.175 us; speedup vs baseline: 1.0982x; 1.0982x over previous
//
#include <hip/hip_runtime.h>
#include <math.h>

#define B_  32
#define LT_ 512
#define LI_ 576
#define LIP 640           // image tokens padded to a multiple of 128
#define D_  768
#define H_  8
#define K_  512
#define NTOK  (LI_ + LT_) // 1088
#define CSPLIT 8
#define TPB   (NTOK / CSPLIT)  // 136 tokens per ctx block
#define NHEAD ((long)H_ * B_ * D_)

typedef __attribute__((ext_vector_type(4))) short short4v;
typedef __attribute__((ext_vector_type(8))) unsigned short ushort8;
typedef __attribute__((ext_vector_type(8))) _Float16 f16x8;
typedef __attribute__((ext_vector_type(4))) float f32x4;

__device__ __forceinline__ unsigned short f2h(float x) {
  _Float16 h = (_Float16)x;                       // RNE
  return __builtin_bit_cast(unsigned short, h);
}
__device__ __forceinline__ float h2f(unsigned short u) {
  return (float)__builtin_bit_cast(_Float16, u);
}
__device__ __forceinline__ float ftanh(float x) {
  float e = __expf(2.f * x);                      // saturates correctly at +-inf
  return 1.f - 2.f * __builtin_amdgcn_rcpf(e + 1.f);
}

__device__ __forceinline__ void gl_lds16(const void* g, void* l) {
  __builtin_amdgcn_global_load_lds(
      (const __attribute__((address_space(1))) void*)g,
      (__attribute__((address_space(3))) void*)l, 16, 0, 0);
}

// inline-asm LDS read: invisible to the compiler's alias analysis, so it does
// NOT force an auto s_waitcnt vmcnt(0) against in-flight global_load_lds.
// Caller MUST issue s_waitcnt lgkmcnt(0) + sched_barrier(0) before consuming
// the result (rule #18).
__device__ __forceinline__ f16x8 lds_read16(const unsigned short* p) {
  f16x8 r;
  const __attribute__((address_space(3))) unsigned short* lp =
      (const __attribute__((address_space(3))) unsigned short*)p;
  asm volatile("ds_read_b128 %0, %1" : "=v"(r) : "v"(lp));
  return r;
}

// ---------------------------------------------------------------------------
// Segmented NT fp16 MFMA GEMM: C[m,n] = sum_k A[m*lda+k]*B[n*ldb+k], k<Kd
// Block tile 128x128, BK=32, 4 waves each owning 64x64 (2x2 wave grid).
// TRIPLE-BUFFERED LDS (3 x 16KB = 48KB -> 3 blocks/CU) + counted-vmcnt
// pipeline (T3+T4) with asm ds_read (no compiler vmcnt drain):
//   prologue: stage(0,t0) stage(1,t1) stage(2,t2)      (12 loads/wave)
//   iter t:   s_waitcnt vmcnt(8|4|0)   own stage done, 2 tiles in flight
//             s_barrier                all waves' slices landed
//             asm ds_read x8 ; lgkmcnt(0) ; sched_barrier(0)
//             setprio(1) ; 16x MFMA ; setprio(0)
//             s_barrier                all reads of buf done
//             stage(buf, t+3)          restage just-consumed buffer
// LDS k-slot swizzle (m97 BK=32 form): slot = chunk ^ ((row>>1)&3) on both
// the pre-swizzled global source column and the read slot (rule #21).
// XCD-swizzled 1D grid (m204). Up to 3 independent segments per dispatch.
// epi: 0=PLAIN fp16 C; 1=T fp16 C + C^T; 2=TANH-dot accumulate; 3=OUT atomic f32
// ---------------------------------------------------------------------------
#define EPI_PLAIN 0
#define EPI_T     1
#define EPI_TANH  2
#define EPI_OUT   3

struct Seg {
  const unsigned short *A, *B;
  unsigned short *C, *CT;
  const unsigned short* base;
  const float* wvec;
  float* outv;
  long sA, sB, sC, sCT, sBase;
  int Kd, lda, ldb;          // lda/ldb: physical row strides (== Kd unless split-K)
  int gx, gy, nblk, epi, Mlim, valid, ldc, ldt;
};
struct Params { Seg s0, s1, s2; };

__global__ __launch_bounds__(256, 3) void mfma_seg(Params p)
{
  // bijective XCD-aware swizzle (m204)
  const int orig = blockIdx.x, nwg = gridDim.x;
  const int q8 = nwg >> 3, r8 = nwg & 7;
  const int xcd = orig & 7, idx = orig >> 3;
  const int wg = (xcd < r8 ? xcd * (q8 + 1) : r8 * (q8 + 1) + (xcd - r8) * q8) + idx;

  Seg sg; int local;
  if (wg < p.s0.nblk)                      { sg = p.s0; local = wg; }
  else if (wg < p.s0.nblk + p.s1.nblk)     { sg = p.s1; local = wg - p.s0.nblk; }
  else                                     { sg = p.s2; local = wg - p.s0.nblk - p.s1.nblk; }

  const int bx = local % sg.gx;
  const int tmp2 = local / sg.gx;
  const int by = tmp2 % sg.gy, bz = tmp2 / sg.gy;

  // 48 KB: three buffers of {A 128x32 (8KB) | B 128x32 (8KB)}
  __shared__ unsigned short LDSU[24576];

  const int t = threadIdx.x, lane = t & 63, w = t >> 6;
  const int wr = w >> 1, wc = w & 1;
  const int m0 = bx * 128, n0 = by * 128;
  const int Kd = sg.Kd, lda = sg.lda, ldb = sg.ldb, ldc = sg.ldc;
  const unsigned short* A  = sg.A + (long)bz * sg.sA;
  const unsigned short* Bm = sg.B + (long)bz * sg.sB;

  // staging (verified round-2/3 mapping): wave w covers rows {w*16+(l>>2),
  // +64} of each 128x32 tile; chunk = l&3; source col pre-swizzled
  // chunk^((row>>1)&3) (row+64 preserves it). LDS dest = uniform + lane*16B.
  const int srow = w * 16 + (lane >> 2);
  const int cswz = ((lane & 3) ^ ((srow >> 1) & 3)) * 8;
  const bool clampA = (m0 + 128 > sg.Mlim);
  const unsigned short* aSrc = A  + (long)(m0 + srow) * lda + cswz;
  const unsigned short* bSrc = Bm + (long)(n0 + srow) * ldb + cswz;
  const int ldsLane = w * 512 + lane * 8;         // ushort offset within tile

  f32x4 acc[4][4];
  #pragma unroll
  for (int i = 0; i < 4; ++i)
    #pragma unroll
    for (int j = 0; j < 4; ++j)
      acc[i][j] = (f32x4){0.f, 0.f, 0.f, 0.f};

  const int rl = lane & 15, g = lane >> 4;
  const int aslot = (g ^ ((rl >> 1) & 3)) << 3;

  auto stage = [&](int bufi, int k0) {
    unsigned short* Ab = LDSU + bufi * 8192;
    unsigned short* Bb = Ab + 4096;
    if (!clampA) {
      gl_lds16(aSrc + k0,                 Ab + ldsLane);
      gl_lds16(aSrc + (long)64 * lda + k0, Ab + ldsLane + 2048);
    } else {
      int r0 = m0 + srow, r1 = r0 + 64;
      if (r0 >= sg.Mlim) r0 = sg.Mlim - 1;
      if (r1 >= sg.Mlim) r1 = sg.Mlim - 1;
      gl_lds16(A + (long)r0 * lda + cswz + k0, Ab + ldsLane);
      gl_lds16(A + (long)r1 * lda + cswz + k0, Ab + ldsLane + 2048);
    }
    gl_lds16(bSrc + k0,                 Bb + ldsLane);
    gl_lds16(bSrc + (long)64 * ldb + k0, Bb + ldsLane + 2048);
  };

  const int nt = Kd >> 5;
  stage(0, 0);
  if (nt > 1) stage(1, 32);
  if (nt > 2) stage(2, 64);
  int cur = 0;
  for (int tt = 0; tt < nt; ++tt) {
    const int ahead = nt - 1 - tt;        // stages still in flight beyond tt
    if (ahead >= 2)      asm volatile("s_waitcnt vmcnt(8)" ::: "memory");
    else if (ahead == 1) asm volatile("s_waitcnt vmcnt(4)" ::: "memory");
    else                 asm volatile("s_waitcnt vmcnt(0)" ::: "memory");
    __builtin_amdgcn_s_barrier();         // all waves' stage(tt) landed

    const unsigned short* Ab = LDSU + cur * 8192;
    const unsigned short* Bb = Ab + 4096;
    f16x8 af[4], bf[4];
    #pragma unroll
    for (int i = 0; i < 4; ++i)
      af[i] = lds_read16(&Ab[(wr * 64 + i * 16 + rl) * 32 + aslot]);
    #pragma unroll
    for (int j = 0; j < 4; ++j)
      bf[j] = lds_read16(&Bb[(wc * 64 + j * 16 + rl) * 32 + aslot]);
    asm volatile("s_waitcnt lgkmcnt(0)" ::: "memory");
    __builtin_amdgcn_sched_barrier(0);    // rule #18: pin MFMA below the wait

    __builtin_amdgcn_s_setprio(1);
    #pragma unroll
    for (int i = 0; i < 4; ++i)
      #pragma unroll
      for (int j = 0; j < 4; ++j)
        acc[i][j] = __builtin_amdgcn_mfma_f32_16x16x32_f16(af[i], bf[j], acc[i][j], 0, 0, 0);
    __builtin_amdgcn_s_setprio(0);

    __builtin_amdgcn_s_barrier();         // all waves done reading buf[cur]
    if (tt + 3 < nt) stage(cur, (tt + 3) << 5);   // restage consumed buffer
    cur = (cur == 2) ? 0 : cur + 1;
  }

  const int rg = lane >> 4;
  if (sg.epi <= EPI_T) {
    unsigned short* C = sg.C + (long)bz * sg.sC;
    unsigned short hv[4][4][4];
    #pragma unroll
    for (int i = 0; i < 4; ++i)
      #pragma unroll
      for (int j = 0; j < 4; ++j)
        #pragma unroll
        for (int rr = 0; rr < 4; ++rr) {
          int ml = wr * 64 + i * 16 + rg * 4 + rr;    // C/D: row=(l>>4)*4+reg
          int nl = wc * 64 + j * 16 + rl;             //      col=l&15
          hv[i][j][rr] = f2h(acc[i][j][rr]);
          if (m0 + ml < sg.Mlim)
            C[(long)(m0 + ml) * ldc + n0 + nl] = hv[i][j][rr];
        }
    if (sg.epi == EPI_T) {
      unsigned short* CT = sg.CT + (long)bz * sg.sCT;
      // K-loop's final s_barrier guarantees LDS is quiescent here.
      #pragma unroll
      for (int i = 0; i < 4; ++i)
        #pragma unroll
        for (int j = 0; j < 4; ++j) {
          int nl = wc * 64 + j * 16 + rl;
          int mh = wr * 64 + i * 16 + rg * 4;
          *(short4v*)&LDSU[nl * 136 + mh] = (short4v){
              (short)hv[i][j][0], (short)hv[i][j][1],
              (short)hv[i][j][2], (short)hv[i][j][3]};
        }
      __syncthreads();
      #pragma unroll
      for (int rr = 0; rr < 8; ++rr) {
        int rn = rr * 16 + (t >> 4);
        int m8 = (t & 15) * 8;
        if (m0 + m8 < sg.Mlim)
          *(ushort8*)(CT + (long)(n0 + rn) * sg.ldt + m0 + m8) =
              *(const ushort8*)&LDSU[rn * 136 + m8];
      }
    }
  } else if (sg.epi == EPI_TANH) {
    const unsigned short* base = sg.base + (long)bz * sg.sBase;
    float* outp = sg.outv + (long)bz * sg.valid;
    #pragma unroll
    for (int i = 0; i < 4; ++i)
      #pragma unroll
      for (int rr = 0; rr < 4; ++rr) {
        int row = m0 + wr * 64 + i * 16 + rg * 4 + rr;  // uniform over rl group
        if (row < sg.Mlim) {
          float s = 0.f;
          #pragma unroll
          for (int j = 0; j < 4; ++j) {
            int col = n0 + wc * 64 + j * 16 + rl;
            float v = acc[i][j][rr] + h2f(base[(long)row * ldc + col]);
            s += ftanh(v) * sg.wvec[col];
          }
          s += __shfl_xor(s, 1, 64);
          s += __shfl_xor(s, 2, 64);
          s += __shfl_xor(s, 4, 64);
          s += __shfl_xor(s, 8, 64);
          if (rl == 0 && row < sg.valid)
            atomicAdd(&outp[row], s);
        }
      }
  } else {  // EPI_OUT: rows < 32 live in wr==0, i<2
    float* outp = sg.outv;
    if (wr == 0) {
      #pragma unroll
      for (int i = 0; i < 2; ++i)
        #pragma unroll
        for (int rr = 0; rr < 4; ++rr) {
          int row = i * 16 + rg * 4 + rr;
          #pragma unroll
          for (int j = 0; j < 4; ++j) {
            int col = n0 + wc * 64 + j * 16 + rl;
            atomicAdd(&outp[(long)row * ldc + col], acc[i][j][rr]);
          }
        }
    }
  }
}

// --------------------------- helper kernels --------------------------------
struct CSeg { const float* src; unsigned short* dst; long n8; };

__global__ __launch_bounds__(256) void cast_multi(
    CSeg c0, CSeg c1, CSeg c2, CSeg c3, CSeg c4)
{
  long i = (long)blockIdx.x * 256 + threadIdx.x;
  const float* src; unsigned short* dst;
  if      (i < c0.n8)                 { src = c0.src; dst = c0.dst; }
  else if ((i -= c0.n8) < c1.n8)      { src = c1.src; dst = c1.dst; }
  else if ((i -= c1.n8) < c2.n8)      { src = c2.src; dst = c2.dst; }
  else if ((i -= c2.n8) < c3.n8)      { src = c3.src; dst = c3.dst; }
  else if ((i -= c3.n8) < c4.n8)      { src = c4.src; dst = c4.dst; }
  else return;
  float4 v0 = ((const float4*)src)[i * 2];
  float4 v1 = ((const float4*)src)[i * 2 + 1];
  ushort8 o;
  o[0] = f2h(v0.x); o[1] = f2h(v0.y); o[2] = f2h(v0.z); o[3] = f2h(v0.w);
  o[4] = f2h(v1.x); o[5] = f2h(v1.y); o[6] = f2h(v1.z); o[7] = f2h(v1.w);
  *(ushort8*)(dst + i * 8) = o;
}

__global__ __launch_bounds__(256) void cast_pad_image(
    const float* __restrict__ in, unsigned short* __restrict__ out)
{
  long tid = (long)blockIdx.x * 256 + threadIdx.x;
  const long tot = (long)B_ * LIP * (D_ / 8);
  if (tid >= tot) return;
  int e8 = (int)(tid % (D_ / 8));
  long rw = tid / (D_ / 8);
  int y  = (int)(rw % LIP);
  long b = rw / LIP;
  ushort8 o;
  if (y < LI_) {
    const float* p = in + ((b * LI_ + y) * D_ + e8 * 8);
    float4 v0 = *(const float4*)p, v1 = *(const float4*)(p + 4);
    o[0] = f2h(v0.x); o[1] = f2h(v0.y); o[2] = f2h(v0.z); o[3] = f2h(v0.w);
    o[4] = f2h(v1.x); o[5] = f2h(v1.y); o[6] = f2h(v1.z); o[7] = f2h(v1.w);
  } else {
    #pragma unroll
    for (int j = 0; j < 8; ++j) o[j] = 0;
  }
  *(ushort8*)(out + rw * D_ + e8 * 8) = o;
}

__global__ __launch_bounds__(256) void zero_f32(float* __restrict__ p, long n) {
  long i = (long)blockIdx.x * 256 + threadIdx.x;
  if (i < n) p[i] = 0.f;
}

// out[b,d] = bo[d]  (bias pre-init; EPI_OUT accumulates on top)
__global__ __launch_bounds__(256) void init_out(
    const float* __restrict__ bo, float* __restrict__ out)
{
  int i = blockIdx.x * 256 + threadIdx.x;   // 96 blocks x 256 = 24576
  out[i] = bo[i % D_];
}

// per (b,h): softmax over LI (lv) and LT (lq) -> normalized att weights
__global__ __launch_bounds__(256) void softmax_att(
    const float* __restrict__ lv, const float* __restrict__ lq,
    float* __restrict__ attvG, float* __restrict__ attqG)
{
  const int b = blockIdx.x, h = blockIdx.y;
  const int t = threadIdx.x;
  __shared__ float buf[LI_];
  __shared__ float red[4];

  const float* lvp = lv + ((long)h * B_ + b) * LI_;
  float m = -1e30f;
  for (int i = t; i < LI_; i += 256) m = fmaxf(m, lvp[i]);
  #pragma unroll
  for (int o = 32; o > 0; o >>= 1) m = fmaxf(m, __shfl_down(m, o, 64));
  if ((t & 63) == 0) red[t >> 6] = m;
  __syncthreads();
  m = fmaxf(fmaxf(red[0], red[1]), fmaxf(red[2], red[3]));
  __syncthreads();
  float s = 0.f;
  for (int i = t; i < LI_; i += 256) { float e = __expf(lvp[i] - m); buf[i] = e; s += e; }
  #pragma unroll
  for (int o = 32; o > 0; o >>= 1) s += __shfl_down(s, o, 64);
  if ((t & 63) == 0) red[t >> 6] = s;
  __syncthreads();
  s = red[0] + red[1] + red[2] + red[3];
  {
    float inv = 1.f / s;
    float* op = attvG + ((long)h * B_ + b) * LI_;
    for (int i = t; i < LI_; i += 256) op[i] = buf[i] * inv;
  }
  __syncthreads();

  const float* lqp = lq + ((long)h * B_ + b) * LT_;
  m = -1e30f;
  for (int i = t; i < LT_; i += 256) m = fmaxf(m, lqp[i]);
  #pragma unroll
  for (int o = 32; o > 0; o >>= 1) m = fmaxf(m, __shfl_down(m, o, 64));
  if ((t & 63) == 0) red[t >> 6] = m;
  __syncthreads();
  m = fmaxf(fmaxf(red[0], red[1]), fmaxf(red[2], red[3]));
  __syncthreads();
  s = 0.f;
  for (int i = t; i < LT_; i += 256) { float e = __expf(lqp[i] - m); buf[i] = e; s += e; }
  #pragma unroll
  for (int o = 32; o > 0; o >>= 1) s += __shfl_down(s, o, 64);
  if ((t & 63) == 0) red[t >> 6] = s;
  __syncthreads();
  s = red[0] + red[1] + red[2] + red[3];
  {
    float inv = 1.f / s;
    float* op = attqG + ((long)h * B_ + b) * LT_;
    for (int i = t; i < LT_; i += 256) op[i] = buf[i] * inv;
  }
}

// partial context: grid (B, D/128, CSPLIT); 256 thr = 128 d-lanes x 2 groups.
__global__ __launch_bounds__(256) void ctx_part(
    const float* __restrict__ attvG, const float* __restrict__ attqG,
    const unsigned short* __restrict__ text_h,   // base; image_p follows
    float* __restrict__ head_part)
{
  const int b = blockIdx.x, d0 = blockIdx.y * 128, s = blockIdx.z;
  const int t = threadIdx.x, dl = t & 127, g = t >> 7;
  const long IMG_OFF = (long)B_ * LT_ * D_;
  __shared__ float wts[H_][TPB];
  __shared__ long  roff[TPB];
  __shared__ float red[H_][128];
  const int tok0 = s * TPB;
  for (int i = t; i < H_ * TPB; i += 256) {
    int h = i / TPB, j = i % TPB, tok = tok0 + j;
    wts[h][j] = tok < LI_ ? attvG[((long)h * B_ + b) * LI_ + tok]
                          : attqG[((long)h * B_ + b) * LT_ + (tok - LI_)];
  }
  if (t < TPB) {
    int tok = tok0 + t;
    roff[t] = tok < LI_ ? IMG_OFF + ((long)b * LIP + tok) * D_
                        : ((long)b * LT_ + (tok - LI_)) * D_;
  }
  __syncthreads();
  float acc[H_];
  #pragma unroll
  for (int h = 0; h < H_; ++h) acc[h] = 0.f;
  #pragma unroll 4
  for (int j = g; j < TPB; j += 2) {
    float val = h2f(text_h[roff[j] + d0 + dl]);
    #pragma unroll
    for (int h = 0; h < H_; ++h) acc[h] = fmaf(wts[h][j], val, acc[h]);
  }
  if (g == 1) {
    #pragma unroll
    for (int h = 0; h < H_; ++h) red[h][dl] = acc[h];
  }
  __syncthreads();
  if (g == 0) {
    float* hp = head_part + (long)s * NHEAD;
    #pragma unroll
    for (int h = 0; h < H_; ++h)
      hp[((long)h * B_ + b) * D_ + d0 + dl] = acc[h] + red[h][dl];
  }
}

// reduce partials -> head16[b][h*D+d] (fp16, layout ready for out-proj GEMM)
__global__ __launch_bounds__(256) void reduce_head(
    const float* __restrict__ head_part, unsigned short* __restrict__ head16)
{
  long i = (long)blockIdx.x * 256 + threadIdx.x;   // over [h][b][d]
  float s = 0.f;
  #pragma unroll
  for (int p = 0; p < CSPLIT; ++p) s += head_part[(long)p * NHEAD + i];
  int d = (int)(i % D_);
  long hb = i / D_;
  int b = (int)(hb % B_), h = (int)(hb / B_);
  head16[(long)b * (H_ * D_) + (long)h * D_ + d] = f2h(s);
}

// ---------------------------------------------------------------------------
extern "C" void kernel_launch(void* const* d_in, const int* in_sizes, int n_in,
                              void* d_out, int out_size, void* d_ws, size_t ws_size,
                              hipStream_t stream)
{
  const float* text  = (const float*)d_in[0];
  const float* image = (const float*)d_in[1];
  const float* Wb  = (const float*)d_in[3];
  const float* Wv  = (const float*)d_in[4];
  const float* Wq  = (const float*)d_in[5];
  const float* Whv = (const float*)d_in[6];
  const float* Whq = (const float*)d_in[7];
  const float* Wo  = (const float*)d_in[8];
  const float* bo  = (const float*)d_in[9];
  float* out = (float*)d_out;

  const long N_TEXT = (long)B_ * LT_ * D_;
  const long N_IMGP = (long)B_ * LIP * D_;
  const long N_WV   = (long)K_ * D_;
  const long N_WB   = (long)H_ * D_ * D_;
  const long N_WO   = (long)D_ * H_ * D_;
  const long N_WVV  = (long)B_ * LIP * K_;
  const long N_WQQ  = (long)B_ * LT_ * K_;
  const long N_PT   = (long)B_ * LT_ * D_;
  const long N_AFF  = (long)B_ * LT_ * LIP;
  const long N_LV   = (long)H_ * B_ * LI_;
  const long N_LQ   = (long)H_ * B_ * LT_;
  const long N_H16  = (long)B_ * H_ * D_;

  unsigned short* wsu = (unsigned short*)d_ws;
  long off = 0;
  unsigned short* text_h  = wsu + off; off += N_TEXT;
  unsigned short* image_p = wsu + off; off += N_IMGP;
  unsigned short* Wv_h    = wsu + off; off += N_WV;
  unsigned short* Wq_h    = wsu + off; off += N_WV;
  unsigned short* Wb_h    = wsu + off; off += N_WB;
  unsigned short* Wo_h    = wsu + off; off += N_WO;
  unsigned short* wv_v    = wsu + off; off += N_WVV;
  unsigned short* wq_q    = wsu + off; off += N_WQQ;
  unsigned short* wv_vT   = wsu + off; off += N_WVV;
  unsigned short* wq_qT   = wsu + off; off += N_WQQ;
  unsigned short* pt_h    = wsu + off; off += N_PT;
  unsigned short* aff     = wsu + off; off += N_AFF;
  unsigned short* affT    = wsu + off; off += N_AFF;
  unsigned short* head16  = wsu + off; off += N_H16;
  float* lv        = (float*)(wsu + off);
  float* lq        = lv + N_LV;
  float* attvG     = lq + N_LQ;
  float* attqG     = attvG + N_LV;
  float* head_part = attqG + N_LQ;
  const size_t need = (size_t)off * 2 +
      (size_t)(2 * (N_LV + N_LQ) + CSPLIT * NHEAD) * 4;
  if (ws_size < need) return;

  dim3 blk(256);

  // ---- casts (one merged dispatch + padded image) ----
  {
    CSeg c0{text, text_h, N_TEXT / 8};
    CSeg c1{Wv,   Wv_h,   N_WV / 8};
    CSeg c2{Wq,   Wq_h,   N_WV / 8};
    CSeg c3{Wb,   Wb_h,   N_WB / 8};
    CSeg c4{Wo,   Wo_h,   N_WO / 8};
    long tot8 = c0.n8 + c1.n8 + c2.n8 + c3.n8 + c4.n8;
    cast_multi<<<(unsigned)((tot8 + 255) / 256), blk, 0, stream>>>(c0, c1, c2, c3, c4);
  }
  cast_pad_image<<<(unsigned)((B_ * LIP * (D_ / 8) + 255) / 256), blk, 0, stream>>>(image, image_p);
  zero_f32<<<(unsigned)((N_LV + N_LQ + 255) / 256), blk, 0, stream>>>(lv, N_LV + N_LQ);
  init_out<<<(unsigned)(B_ * D_ / 256), blk, 0, stream>>>(bo, out);

  Seg zs{};  zs.nblk = 0;

  // ---- G1: wv_v(+T), wq_q(+T), pt[0] ----  (128x128 tiles)
  {
    Seg s0{}; s0.A = image_p; s0.B = Wv_h; s0.C = wv_v; s0.CT = wv_vT;
    s0.sA = (long)LIP * D_; s0.sC = (long)LIP * K_; s0.sCT = (long)K_ * LIP;
    s0.Kd = D_; s0.lda = D_; s0.ldb = D_;
    s0.gx = 5; s0.gy = 4; s0.nblk = 5 * 4 * B_; s0.epi = EPI_T;
    s0.Mlim = LIP; s0.ldc = K_; s0.ldt = LIP;

    Seg s1{}; s1.A = text_h; s1.B = Wq_h; s1.C = wq_q; s1.CT = wq_qT;
    s1.sA = (long)LT_ * D_; s1.sC = (long)LT_ * K_; s1.sCT = (long)K_ * LT_;
    s1.Kd = D_; s1.lda = D_; s1.ldb = D_;
    s1.gx = 4; s1.gy = 4; s1.nblk = 4 * 4 * B_; s1.epi = EPI_T;
    s1.Mlim = LT_; s1.ldc = K_; s1.ldt = LT_;

    Seg s2{}; s2.A = text_h; s2.B = Wb_h; s2.C = pt_h;
    s2.Kd = D_; s2.lda = D_; s2.ldb = D_;
    s2.gx = 128; s2.gy = 6; s2.nblk = 128 * 6; s2.epi = EPI_PLAIN;
    s2.Mlim = B_ * LT_; s2.ldc = D_;

    Params P{s0, s1, s2};
    mfma_seg<<<s0.nblk + s1.nblk + s2.nblk, blk, 0, stream>>>(P);
  }

  for (int h = 0; h < H_; ++h) {
    // aff[h] (+ affT)
    {
      Seg s0{}; s0.A = pt_h; s0.B = image_p; s0.C = aff; s0.CT = affT;
      s0.sA = (long)LT_ * D_; s0.sB = (long)LIP * D_;
      s0.sC = (long)LT_ * LIP; s0.sCT = (long)LIP * LT_;
      s0.Kd = D_; s0.lda = D_; s0.ldb = D_;
      s0.gx = 4; s0.gy = 5; s0.nblk = 4 * 5 * B_; s0.epi = EPI_T;
      s0.Mlim = LT_; s0.ldc = LIP; s0.ldt = LT_;
      Params P{s0, zs, zs};
      mfma_seg<<<s0.nblk, blk, 0, stream>>>(P);
    }
    // wqqc-tanh + wvvc-tanh + pt[h+1]
    {
      Seg s0{}; s0.A = affT; s0.B = wq_qT;
      s0.base = wv_v; s0.wvec = Whv; s0.outv = lv + (long)h * B_ * LI_;
      s0.sA = (long)LIP * LT_; s0.sB = (long)K_ * LT_; s0.sBase = (long)LIP * K_;
      s0.Kd = LT_; s0.lda = LT_; s0.ldb = LT_;
      s0.gx = 5; s0.gy = 4; s0.nblk = 5 * 4 * B_; s0.epi = EPI_TANH;
      s0.Mlim = LIP; s0.valid = LI_; s0.ldc = K_;

      Seg s1{}; s1.A = aff; s1.B = wv_vT;
      s1.base = wq_q; s1.wvec = Whq; s1.outv = lq + (long)h * B_ * LT_;
      s1.sA = (long)LT_ * LIP; s1.sB = (long)K_ * LIP; s1.sBase = (long)LT_ * K_;
      s1.Kd = LIP; s1.lda = LIP; s1.ldb = LIP;
      s1.gx = 4; s1.gy = 4; s1.nblk = 4 * 4 * B_; s1.epi = EPI_TANH;
      s1.Mlim = LT_; s1.valid = LT_; s1.ldc = K_;

      Seg s2 = zs;
      if (h < H_ - 1) {
        s2.A = text_h; s2.B = Wb_h + (long)(h + 1) * D_ * D_; s2.C = pt_h;
        s2.Kd = D_; s2.lda = D_; s2.ldb = D_;
        s2.gx = 128; s2.gy = 6; s2.nblk = 128 * 6; s2.epi = EPI_PLAIN;
        s2.Mlim = B_ * LT_; s2.ldc = D_;
      }
      Params P{s0, s1, s2};
      mfma_seg<<<s0.nblk + s1.nblk + s2.nblk, blk, 0, stream>>>(P);
    }
  }

  softmax_att<<<dim3(B_, H_), blk, 0, stream>>>(lv, lq, attvG, attqG);
  ctx_part<<<dim3(B_, D_ / 128, CSPLIT), blk, 0, stream>>>(attvG, attqG, text_h, head_part);
  reduce_head<<<(unsigned)(NHEAD / 256), blk, 0, stream>>>(head_part, head16);

  // out[b,d] += sum_k head16[b,k] * Wo_h[d,k]  (K split 8 ways via bz;
  // physical row stride H_*D_ decoupled from per-slice Kd)
  {
    Seg s0{}; s0.A = head16; s0.B = Wo_h; s0.outv = out;
    s0.sA = (long)(H_ * D_ / 8); s0.sB = (long)(H_ * D_ / 8);
    s0.Kd = H_ * D_ / 8; s0.lda = H_ * D_; s0.ldb = H_ * D_;
    s0.gx = 1; s0.gy = 6; s0.nblk = 1 * 6 * 8; s0.epi = EPI_OUT;
    s0.Mlim = B_; s0.valid = B_; s0.ldc = D_;
    Params P{s0, zs, zs};
    mfma_seg<<<s0.nblk, blk, 0, stream>>>(P);
  }
}